// Round 1
// baseline (1247.667 us; speedup 1.0000x reference)
//
#include <hip/hip_runtime.h>
#include <stdint.h>

typedef unsigned short u16;
typedef __bf16 bf16x8 __attribute__((ext_vector_type(8)));
typedef float f32x4 __attribute__((ext_vector_type(4)));

#define NTOK 8192
#define DD 512
#define CHK 512
#define NCH 16
#define LOG2E 1.4426950408889634f
#define SCL 0.044194173824159216f  // 1/sqrt(512)

__device__ __forceinline__ u16 f2bf(float f) {
  union { float f; uint32_t u; } v; v.f = f;
  uint32_t r = v.u + 0x7FFFu + ((v.u >> 16) & 1u);
  return (u16)(r >> 16);
}

// ---------------- cast x -> bf16 ----------------
__global__ void cast_x_kernel(const float* __restrict__ x, u16* __restrict__ xb, int n4) {
  int i = blockIdx.x * blockDim.x + threadIdx.x;
  if (i >= n4) return;
  float4 v = ((const float4*)x)[i];
  ushort4 o;
  o.x = f2bf(v.x); o.y = f2bf(v.y); o.z = f2bf(v.z); o.w = f2bf(v.w);
  ((ushort4*)xb)[i] = o;
}

// ---------------- transpose W (fp32) -> WT bf16 [n][k] ----------------
__global__ void transW_kernel(const float* __restrict__ W, u16* __restrict__ WT) {
  __shared__ float t[32][33];
  int k0 = blockIdx.y * 32, n0 = blockIdx.x * 32;
  int tx = threadIdx.x, ty = threadIdx.y;  // 32 x 8
  #pragma unroll
  for (int i = 0; i < 4; i++)
    t[ty + 8 * i][tx] = W[(k0 + ty + 8 * i) * DD + n0 + tx];
  __syncthreads();
  #pragma unroll
  for (int i = 0; i < 4; i++)
    WT[(n0 + ty + 8 * i) * DD + k0 + tx] = f2bf(t[tx][ty + 8 * i]);
}

// ---------------- GEMM: C[8192x512] = A(bf16) @ BT(bf16,[n][k]) + bias ----------------
// MODE 0: bf16 row-major out; MODE 1: bf16 transposed out [n][m]; MODE 2: fp32 out + resid
template <int MODE>
__launch_bounds__(256, 3)
__global__ void gemm512_kernel(const u16* __restrict__ A, const u16* __restrict__ BT,
                               const float* __restrict__ bias, void* __restrict__ outp,
                               const float* __restrict__ resid) {
  const int m0 = blockIdx.x * 64;
  const int n0 = blockIdx.y * 128;
  const int tid = threadIdx.x;
  const int w = tid >> 6, lane = tid & 63;
  const int lm = lane & 15, quad = lane >> 4;
  const u16* Ab = A + (m0 + w * 16 + lm) * DD;
  const u16* Bb = BT + (n0 + lm) * DD;
  f32x4 acc[8] = {};
  for (int kk = 0; kk < DD; kk += 32) {
    bf16x8 af = *(const bf16x8*)(Ab + kk + quad * 8);
    #pragma unroll
    for (int nt = 0; nt < 8; nt++) {
      bf16x8 bfr = *(const bf16x8*)(Bb + nt * 16 * DD + kk + quad * 8);
      acc[nt] = __builtin_amdgcn_mfma_f32_16x16x32_bf16(af, bfr, acc[nt], 0, 0, 0);
    }
  }
  const int orow0 = m0 + w * 16 + quad * 4;
  #pragma unroll
  for (int nt = 0; nt < 8; nt++) {
    const int ncol = n0 + nt * 16 + lm;
    const float bv = bias[ncol];
    if (MODE == 1) {
      u16 st[4];
      #pragma unroll
      for (int r = 0; r < 4; r++) st[r] = f2bf(acc[nt][r] + bv);
      ushort4 o; o.x = st[0]; o.y = st[1]; o.z = st[2]; o.w = st[3];
      *(ushort4*)((u16*)outp + ncol * NTOK + orow0) = o;
    } else {
      #pragma unroll
      for (int r = 0; r < 4; r++) {
        const int idx = (orow0 + r) * DD + ncol;
        if (MODE == 0) ((u16*)outp)[idx] = f2bf(acc[nt][r] + bv);
        else ((float*)outp)[idx] = acc[nt][r] + bv + resid[idx];
      }
    }
  }
}

// ---------------- fused attention ----------------
// block: 512 threads (8 waves), 32 q-rows; wave w: mt=w&1 (16-row Mtile), nq=w>>1 (128-key/d quarter)
__launch_bounds__(512, 2)
__global__ void attn_kernel(const u16* __restrict__ qb, const u16* __restrict__ kb,
                            const u16* __restrict__ vT, u16* __restrict__ attnb) {
  __shared__ __align__(16) u16 P[32 * 520];
  __shared__ float hmax[4][32];
  __shared__ float hsum[4][32];
  __shared__ float lpart[4][32];
  const int m0 = blockIdx.x * 32;
  const int tid = threadIdx.x;
  const int w = tid >> 6, lane = tid & 63;
  const int lm = lane & 15, quad = lane >> 4;
  const int mt = w & 1, nq = w >> 1;
  const u16* Ab = qb + (m0 + mt * 16 + lm) * DD;
  const int lr0 = mt * 16 + quad * 4;
  f32x4 oacc[8] = {};
  float lacc[4] = {0.f, 0.f, 0.f, 0.f};

  for (int c = 0; c < NCH; c++) {
    // ---- S = q @ k^T for this chunk (quarter of keys per wave) ----
    f32x4 s[8] = {};
    const u16* Kb = kb + (c * CHK + nq * 128 + lm) * DD;
    for (int kk = 0; kk < DD; kk += 32) {
      bf16x8 af = *(const bf16x8*)(Ab + kk + quad * 8);
      #pragma unroll
      for (int nt = 0; nt < 8; nt++) {
        bf16x8 bfr = *(const bf16x8*)(Kb + nt * 16 * DD + kk + quad * 8);
        s[nt] = __builtin_amdgcn_mfma_f32_16x16x32_bf16(af, bfr, s[nt], 0, 0, 0);
      }
    }
    // ---- per-row quarter max & exp-sum ----
    float mrow[4], zrow[4];
    #pragma unroll
    for (int r = 0; r < 4; r++) {
      float m = -1e30f;
      #pragma unroll
      for (int nt = 0; nt < 8; nt++) { s[nt][r] *= SCL; m = fmaxf(m, s[nt][r]); }
      #pragma unroll
      for (int off = 1; off < 16; off <<= 1) m = fmaxf(m, __shfl_xor(m, off, 64));
      float z = 0.f;
      #pragma unroll
      for (int nt = 0; nt < 8; nt++) {
        float e = exp2f((s[nt][r] - m) * LOG2E);
        s[nt][r] = e; z += e;
      }
      #pragma unroll
      for (int off = 1; off < 16; off <<= 1) z += __shfl_xor(z, off, 64);
      mrow[r] = m; zrow[r] = z;
    }
    if (lm == 0) {
      #pragma unroll
      for (int r = 0; r < 4; r++) { hmax[nq][lr0 + r] = mrow[r]; hsum[nq][lr0 + r] = zrow[r]; }
    }
    __syncthreads();
    // ---- combine quarters; w1 = exp(s-M)/Z; p = exp(w1); write P, accum l ----
    #pragma unroll
    for (int r = 0; r < 4; r++) {
      const int lr = lr0 + r;
      float M = fmaxf(fmaxf(hmax[0][lr], hmax[1][lr]), fmaxf(hmax[2][lr], hmax[3][lr]));
      float Z = hsum[0][lr] * exp2f((hmax[0][lr] - M) * LOG2E)
              + hsum[1][lr] * exp2f((hmax[1][lr] - M) * LOG2E)
              + hsum[2][lr] * exp2f((hmax[2][lr] - M) * LOG2E)
              + hsum[3][lr] * exp2f((hmax[3][lr] - M) * LOG2E);
      const float fac = exp2f((mrow[r] - M) * LOG2E) / Z;
      #pragma unroll
      for (int nt = 0; nt < 8; nt++) {
        const float w1 = s[nt][r] * fac;       // in [0,1]
        const float p = exp2f(w1 * LOG2E);     // exp(w1), safe without max-sub
        lacc[r] += p;
        P[lr * 520 + nq * 128 + nt * 16 + lm] = f2bf(p);
      }
    }
    __syncthreads();
    // ---- O += P @ V_chunk ----
    const u16* Vb = vT + (nq * 128 + lm) * NTOK + c * CHK;
    const u16* Pb = &P[(mt * 16 + lm) * 520];
    for (int kk = 0; kk < CHK; kk += 32) {
      bf16x8 pf = *(const bf16x8*)(Pb + kk + quad * 8);
      #pragma unroll
      for (int nt = 0; nt < 8; nt++) {
        bf16x8 vf = *(const bf16x8*)(Vb + nt * 16 * NTOK + kk + quad * 8);
        oacc[nt] = __builtin_amdgcn_mfma_f32_16x16x32_bf16(pf, vf, oacc[nt], 0, 0, 0);
      }
    }
    __syncthreads();
  }
  // ---- finalize l and store attn = O / l (bf16) ----
  #pragma unroll
  for (int r = 0; r < 4; r++) {
    float z = lacc[r];
    #pragma unroll
    for (int off = 1; off < 16; off <<= 1) z += __shfl_xor(z, off, 64);
    if (lm == 0) lpart[nq][lr0 + r] = z;
  }
  __syncthreads();
  #pragma unroll
  for (int r = 0; r < 4; r++) {
    const int lr = lr0 + r;
    const float linv = 1.0f / (lpart[0][lr] + lpart[1][lr] + lpart[2][lr] + lpart[3][lr]);
    #pragma unroll
    for (int nt = 0; nt < 8; nt++)
      attnb[(m0 + lr) * DD + nq * 128 + nt * 16 + lm] = f2bf(oacc[nt][r] * linv);
  }
}

// ---------------- cls row (exact fp32): s0 = x @ (Wk q0) + q0.bk ----------------
__global__ void cls_prep_kernel(const float* __restrict__ x, const float* __restrict__ Wq,
                                const float* __restrict__ bq, const float* __restrict__ Wk,
                                const float* __restrict__ bk, float* __restrict__ uc) {
  __shared__ float q0[512];
  int t = threadIdx.x;  // 512
  float acc = bq[t];
  for (int i = 0; i < 512; i++) acc += x[i] * Wq[i * 512 + t];
  q0[t] = acc;
  __syncthreads();
  float u = 0.f;
  for (int j = 0; j < 512; j++) u += Wk[t * 512 + j] * q0[j];
  uc[t] = u;
  if (t == 0) {
    float c = 0.f;
    for (int j = 0; j < 512; j++) c += bk[j] * q0[j];
    uc[512] = c;
  }
}

__global__ void cls_scores_kernel(const float* __restrict__ x, const float* __restrict__ uc,
                                  float* __restrict__ s0) {
  __shared__ float u[512];
  __shared__ float c0s;
  int tid = threadIdx.x;  // 256
  for (int i = tid; i < 512; i += 256) u[i] = uc[i];
  if (tid == 0) c0s = uc[512];
  __syncthreads();
  int rowg = blockIdx.x * 32 + (tid >> 3);
  int ii = tid & 7;
  const float* xr = x + rowg * 512;
  float acc = 0.f;
  for (int i = ii; i < 512; i += 8) acc += xr[i] * u[i];
  acc += __shfl_xor(acc, 1, 64);
  acc += __shfl_xor(acc, 2, 64);
  acc += __shfl_xor(acc, 4, 64);
  if (ii == 0) s0[rowg] = (acc + c0s) * SCL;
}

__global__ void cls_softmax_kernel(const float* __restrict__ s0, float* __restrict__ out) {
  int tid = threadIdx.x;  // 1024 = 16 waves, wave w = chunk w
  int w = tid >> 6, lane = tid & 63;
  const float* sc = s0 + w * 512;
  float v[8];
  float m = -1e30f;
  #pragma unroll
  for (int j = 0; j < 8; j++) { v[j] = sc[lane * 8 + j]; m = fmaxf(m, v[j]); }
  for (int off = 1; off < 64; off <<= 1) m = fmaxf(m, __shfl_xor(m, off, 64));
  float z = 0.f;
  #pragma unroll
  for (int j = 0; j < 8; j++) { v[j] = expf(v[j] - m); z += v[j]; }
  for (int off = 1; off < 64; off <<= 1) z += __shfl_xor(z, off, 64);
  float invz = 1.f / z;
  float l = 0.f;
  #pragma unroll
  for (int j = 0; j < 8; j++) { v[j] = expf(v[j] * invz); l += v[j]; }
  for (int off = 1; off < 64; off <<= 1) l += __shfl_xor(l, off, 64);
  __shared__ float lw[16];
  if (lane == 0) lw[w] = l;
  __syncthreads();
  float L = 0.f;
  for (int i = 0; i < 16; i++) L += lw[i];
  float invL = 1.f / L;
  #pragma unroll
  for (int j = 0; j < 8; j++) out[w * 512 + lane * 8 + j] = v[j] * invL;
}

extern "C" void kernel_launch(void* const* d_in, const int* in_sizes, int n_in,
                              void* d_out, int out_size, void* d_ws, size_t ws_size,
                              hipStream_t stream) {
  const float* x  = (const float*)d_in[0];
  const float* Wq = (const float*)d_in[1];
  const float* bq = (const float*)d_in[2];
  const float* Wk = (const float*)d_in[3];
  const float* bk = (const float*)d_in[4];
  const float* Wv = (const float*)d_in[5];
  const float* bv = (const float*)d_in[6];
  const float* Wo = (const float*)d_in[7];
  const float* bo = (const float*)d_in[8];
  float* out = (float*)d_out;

  char* ws = (char*)d_ws;
  u16* xb    = (u16*)(ws);
  u16* WqT   = (u16*)(ws + 8388608);
  u16* WkT   = (u16*)(ws + 8912896);
  u16* WvT   = (u16*)(ws + 9437184);
  u16* WoT   = (u16*)(ws + 9961472);
  u16* qb    = (u16*)(ws + 10485760);
  u16* kb    = (u16*)(ws + 18874368);
  u16* vT    = (u16*)(ws + 27262976);
  u16* attnb = (u16*)(ws + 35651584);
  float* uc  = (float*)(ws + 44040192);   // 513 floats
  float* s0  = (float*)(ws + 44043264);   // 8192 floats

  cast_x_kernel<<<4096, 256, 0, stream>>>(x, xb, NTOK * DD / 4);
  dim3 tb(32, 8), tg(16, 16);
  transW_kernel<<<tg, tb, 0, stream>>>(Wq, WqT);
  transW_kernel<<<tg, tb, 0, stream>>>(Wk, WkT);
  transW_kernel<<<tg, tb, 0, stream>>>(Wv, WvT);
  transW_kernel<<<tg, tb, 0, stream>>>(Wo, WoT);

  dim3 gg(NTOK / 64, 4);
  gemm512_kernel<0><<<gg, 256, 0, stream>>>(xb, WqT, bq, qb, nullptr);
  gemm512_kernel<0><<<gg, 256, 0, stream>>>(xb, WkT, bk, kb, nullptr);
  gemm512_kernel<1><<<gg, 256, 0, stream>>>(xb, WvT, bv, vT, nullptr);

  attn_kernel<<<NTOK / 32, 512, 0, stream>>>(qb, kb, vT, attnb);

  gemm512_kernel<2><<<gg, 256, 0, stream>>>(attnb, WoT, bo, out, x);

  cls_prep_kernel<<<1, 512, 0, stream>>>(x, Wq, bq, Wk, bk, uc);
  cls_scores_kernel<<<NTOK / 32, 256, 0, stream>>>(x, uc, s0);
  cls_softmax_kernel<<<1, 1024, 0, stream>>>(s0, out + (size_t)NTOK * DD);
}

// Round 2
// 532.561 us; speedup vs baseline: 2.3428x; 2.3428x over previous
//
#include <hip/hip_runtime.h>
#include <stdint.h>

typedef unsigned short u16;
typedef __bf16 bf16x8 __attribute__((ext_vector_type(8)));
typedef float f32x4 __attribute__((ext_vector_type(4)));

#define NTOK 8192
#define DD 512
#define CHK 512
#define NCH 16
#define LOG2E 1.4426950408889634f
#define SCL 0.044194173824159216f  // 1/sqrt(512)

__device__ __forceinline__ u16 f2bf(float f) {
  union { float f; uint32_t u; } v; v.f = f;
  uint32_t r = v.u + 0x7FFFu + ((v.u >> 16) & 1u);
  return (u16)(r >> 16);
}

// async global->LDS, 16B per lane. LDS dest is wave-uniform base + lane*16.
typedef const __attribute__((address_space(1))) unsigned int* gas_t;
typedef __attribute__((address_space(3))) unsigned int* las_t;
__device__ __forceinline__ void gload16(const void* g, void* l) {
  __builtin_amdgcn_global_load_lds((gas_t)g, (las_t)l, 16, 0, 0);
}

// ---------------- cast x -> bf16 ----------------
__global__ void cast_x_kernel(const float* __restrict__ x, u16* __restrict__ xb, int n4) {
  int i = blockIdx.x * blockDim.x + threadIdx.x;
  if (i >= n4) return;
  float4 v = ((const float4*)x)[i];
  ushort4 o;
  o.x = f2bf(v.x); o.y = f2bf(v.y); o.z = f2bf(v.z); o.w = f2bf(v.w);
  ((ushort4*)xb)[i] = o;
}

// ---------------- transpose W (fp32) -> WT bf16 [n][k] ----------------
__global__ void transW_kernel(const float* __restrict__ W, u16* __restrict__ WT) {
  __shared__ float t[32][33];
  int k0 = blockIdx.y * 32, n0 = blockIdx.x * 32;
  int tx = threadIdx.x, ty = threadIdx.y;  // 32 x 8
  #pragma unroll
  for (int i = 0; i < 4; i++)
    t[ty + 8 * i][tx] = W[(k0 + ty + 8 * i) * DD + n0 + tx];
  __syncthreads();
  #pragma unroll
  for (int i = 0; i < 4; i++)
    WT[(n0 + ty + 8 * i) * DD + k0 + tx] = f2bf(t[tx][ty + 8 * i]);
}

__global__ void zero_l_kernel(float* __restrict__ l) {
  l[blockIdx.x * 256 + threadIdx.x] = 0.f;
}

// ---------------- m97-style GEMM: C[128x128 tiles] = A @ BT, LDS-staged ----------------
// MODE 0: bf16 out row-major + bias; MODE 1: bf16 out transposed [n][m] + bias;
// MODE 2: fp32 out + bias + resid; MODE 3: bf16 out row-major, scaled by 1/lsum[row]
template <int MODE>
__launch_bounds__(256, 3)
__global__ void gemm_lds_kernel(const u16* __restrict__ A, const u16* __restrict__ BT,
                                int K, int lda, int ldb,
                                const float* __restrict__ bias, void* __restrict__ outp,
                                const float* __restrict__ resid, const float* __restrict__ lsum) {
  __shared__ __align__(16) u16 As[128 * 32];
  __shared__ __align__(16) u16 Bs[128 * 32];
  const int m0 = blockIdx.x * 128, n0 = blockIdx.y * 128;
  const int tid = threadIdx.x;
  const int w = tid >> 6, lane = tid & 63, lm = lane & 15, quad = lane >> 4;
  const int wm = w & 1, wn = w >> 1;
  f32x4 acc[4][4] = {};
  // staging geometry: round r covers tile bytes [r*4096 + tid*16); row = 64B
  const int soff = tid * 16;
  const int srow = soff >> 6;
  const int scol = soff & 63;
  const char* Ag = (const char*)A + ((size_t)(m0 + srow) * lda) * 2 + scol;
  const char* Bg = (const char*)BT + ((size_t)(n0 + srow) * ldb) * 2 + scol;
  char* Al = (char*)As + w * 1024;
  char* Bl = (char*)Bs + w * 1024;
  const size_t ars = (size_t)64 * lda * 2;
  const size_t brs = (size_t)64 * ldb * 2;
  for (int kk = 0; kk < K; kk += 32) {
    const char* ag = Ag + (size_t)kk * 2;
    const char* bg = Bg + (size_t)kk * 2;
    gload16(ag, Al);
    gload16(ag + ars, Al + 4096);
    gload16(bg, Bl);
    gload16(bg + brs, Bl + 4096);
    __syncthreads();
    bf16x8 af[4], bfr[4];
    #pragma unroll
    for (int i = 0; i < 4; i++) af[i] = *(const bf16x8*)&As[(wm * 64 + i * 16 + lm) * 32 + quad * 8];
    #pragma unroll
    for (int j = 0; j < 4; j++) bfr[j] = *(const bf16x8*)&Bs[(wn * 64 + j * 16 + lm) * 32 + quad * 8];
    #pragma unroll
    for (int i = 0; i < 4; i++)
      #pragma unroll
      for (int j = 0; j < 4; j++)
        acc[i][j] = __builtin_amdgcn_mfma_f32_16x16x32_bf16(af[i], bfr[j], acc[i][j], 0, 0, 0);
    __syncthreads();
  }
  #pragma unroll
  for (int i = 0; i < 4; i++) {
    const int row0 = m0 + wm * 64 + i * 16 + quad * 4;
    float li[4];
    if (MODE == 3) {
      #pragma unroll
      for (int r = 0; r < 4; r++) li[r] = 1.0f / lsum[row0 + r];
    }
    #pragma unroll
    for (int j = 0; j < 4; j++) {
      const int col = n0 + wn * 64 + j * 16 + lm;
      if (MODE == 0) {
        const float bv = bias[col];
        #pragma unroll
        for (int r = 0; r < 4; r++)
          ((u16*)outp)[(size_t)(row0 + r) * DD + col] = f2bf(acc[i][j][r] + bv);
      } else if (MODE == 1) {
        const float bv = bias[col];
        ushort4 o;
        o.x = f2bf(acc[i][j][0] + bv); o.y = f2bf(acc[i][j][1] + bv);
        o.z = f2bf(acc[i][j][2] + bv); o.w = f2bf(acc[i][j][3] + bv);
        *(ushort4*)((u16*)outp + (size_t)col * NTOK + row0) = o;
      } else if (MODE == 2) {
        const float bv = bias[col];
        #pragma unroll
        for (int r = 0; r < 4; r++) {
          const size_t idx = (size_t)(row0 + r) * DD + col;
          ((float*)outp)[idx] = acc[i][j][r] + bv + resid[idx];
        }
      } else {
        #pragma unroll
        for (int r = 0; r < 4; r++)
          ((u16*)outp)[(size_t)(row0 + r) * DD + col] = f2bf(acc[i][j][r] * li[r]);
      }
    }
  }
}

// ---------------- pass A: S = Q@K^T (one 512-chunk per block), chunk softmax, P=exp(w1) ----------------
// 512 threads = 8 waves; block tile 64 rows x 512 cols; wave w owns cols [w*64, w*64+64)
__launch_bounds__(512, 4)
__global__ void scores_kernel(const u16* __restrict__ qb, const u16* __restrict__ kb,
                              u16* __restrict__ P, float* __restrict__ lsum) {
  __shared__ __align__(16) u16 As[64 * 32];    // 4 KB  (64 q-rows x 32 k)
  __shared__ __align__(16) u16 Bs[512 * 32];   // 32 KB (512 keys x 32 k)
  __shared__ float hM[8][64], hS[8][64], hP[8][64];
  const int m0 = blockIdx.x * 64;
  const int c = blockIdx.y;
  const int tid = threadIdx.x;
  const int w = tid >> 6, lane = tid & 63, lm = lane & 15, quad = lane >> 4;
  f32x4 s[4][4] = {};
  const int soff = tid * 16;
  const int srow = soff >> 6;   // 0..127 (A uses only tid<256 -> 0..63)
  const int scol = soff & 63;
  const char* Qg = (const char*)qb + ((size_t)(m0 + srow) * DD) * 2 + scol;
  const char* Kg = (const char*)kb + ((size_t)(c * CHK + srow) * DD) * 2 + scol;
  const size_t krs = (size_t)128 * DD * 2;  // 128 key-rows per staging round
  char* Al = (char*)As + w * 1024;
  char* Bl = (char*)Bs + w * 1024;
  for (int kk = 0; kk < DD; kk += 32) {
    if (tid < 256) gload16(Qg + (size_t)kk * 2, Al);
    #pragma unroll
    for (int r = 0; r < 4; r++)
      gload16(Kg + (size_t)kk * 2 + r * krs, Bl + r * 8192);
    __syncthreads();
    bf16x8 af[4], bfr[4];
    #pragma unroll
    for (int i = 0; i < 4; i++) af[i] = *(const bf16x8*)&As[(i * 16 + lm) * 32 + quad * 8];
    #pragma unroll
    for (int j = 0; j < 4; j++) bfr[j] = *(const bf16x8*)&Bs[(w * 64 + j * 16 + lm) * 32 + quad * 8];
    #pragma unroll
    for (int i = 0; i < 4; i++)
      #pragma unroll
      for (int j = 0; j < 4; j++)
        s[i][j] = __builtin_amdgcn_mfma_f32_16x16x32_bf16(af[i], bfr[j], s[i][j], 0, 0, 0);
    __syncthreads();
  }
  // ---- chunk softmax: local (per-wave 64-col) max & exp-sum ----
  #pragma unroll
  for (int i = 0; i < 4; i++) {
    #pragma unroll
    for (int reg = 0; reg < 4; reg++) {
      float m = -1e30f;
      #pragma unroll
      for (int j = 0; j < 4; j++) {
        float v = s[i][j][reg] * SCL;
        s[i][j][reg] = v;
        m = fmaxf(m, v);
      }
      #pragma unroll
      for (int off = 1; off < 16; off <<= 1) m = fmaxf(m, __shfl_xor(m, off, 64));
      float z = 0.f;
      #pragma unroll
      for (int j = 0; j < 4; j++) {
        float e = exp2f((s[i][j][reg] - m) * LOG2E);
        s[i][j][reg] = e;
        z += e;
      }
      #pragma unroll
      for (int off = 1; off < 16; off <<= 1) z += __shfl_xor(z, off, 64);
      if (lm == 0) {
        const int rl = i * 16 + quad * 4 + reg;
        hM[w][rl] = m; hS[w][rl] = z;
      }
    }
  }
  __syncthreads();
  // ---- combine waves: w1 = exp(s-M)/Z, p = exp(w1), store P, partial l ----
  #pragma unroll
  for (int i = 0; i < 4; i++) {
    #pragma unroll
    for (int reg = 0; reg < 4; reg++) {
      const int rl = i * 16 + quad * 4 + reg;
      float M = hM[0][rl];
      #pragma unroll
      for (int w2 = 1; w2 < 8; w2++) M = fmaxf(M, hM[w2][rl]);
      float Z = 0.f;
      #pragma unroll
      for (int w2 = 0; w2 < 8; w2++) Z += hS[w2][rl] * exp2f((hM[w2][rl] - M) * LOG2E);
      const float fac = exp2f((hM[w][rl] - M) * LOG2E) / Z;
      float zp = 0.f;
      u16* Pr = P + (size_t)(m0 + rl) * NTOK + c * CHK + w * 64;
      #pragma unroll
      for (int j = 0; j < 4; j++) {
        const float p = exp2f(s[i][j][reg] * fac * LOG2E);  // exp(w1), w1 in [0,1]
        zp += p;
        Pr[j * 16 + lm] = f2bf(p);
      }
      #pragma unroll
      for (int off = 1; off < 16; off <<= 1) zp += __shfl_xor(zp, off, 64);
      if (lm == 0) hP[w][rl] = zp;
    }
  }
  __syncthreads();
  if (tid < 64) {
    float t = 0.f;
    #pragma unroll
    for (int w2 = 0; w2 < 8; w2++) t += hP[w2][tid];
    atomicAdd(&lsum[m0 + tid], t);
  }
}

// ---------------- R1 fallback fused attention (used only if ws too small for P) ----------------
__launch_bounds__(512, 2)
__global__ void attn_kernel(const u16* __restrict__ qb, const u16* __restrict__ kb,
                            const u16* __restrict__ vT, u16* __restrict__ attnb) {
  __shared__ __align__(16) u16 P[32 * 520];
  __shared__ float hmax[4][32];
  __shared__ float hsum[4][32];
  __shared__ float lpart[4][32];
  const int m0 = blockIdx.x * 32;
  const int tid = threadIdx.x;
  const int w = tid >> 6, lane = tid & 63;
  const int lm = lane & 15, quad = lane >> 4;
  const int mt = w & 1, nq = w >> 1;
  const u16* Ab = qb + (m0 + mt * 16 + lm) * DD;
  const int lr0 = mt * 16 + quad * 4;
  f32x4 oacc[8] = {};
  float lacc[4] = {0.f, 0.f, 0.f, 0.f};
  for (int c = 0; c < NCH; c++) {
    f32x4 s[8] = {};
    const u16* Kb = kb + (c * CHK + nq * 128 + lm) * DD;
    for (int kk = 0; kk < DD; kk += 32) {
      bf16x8 af = *(const bf16x8*)(Ab + kk + quad * 8);
      #pragma unroll
      for (int nt = 0; nt < 8; nt++) {
        bf16x8 bfr = *(const bf16x8*)(Kb + nt * 16 * DD + kk + quad * 8);
        s[nt] = __builtin_amdgcn_mfma_f32_16x16x32_bf16(af, bfr, s[nt], 0, 0, 0);
      }
    }
    float mrow[4], zrow[4];
    #pragma unroll
    for (int r = 0; r < 4; r++) {
      float m = -1e30f;
      #pragma unroll
      for (int nt = 0; nt < 8; nt++) { s[nt][r] *= SCL; m = fmaxf(m, s[nt][r]); }
      #pragma unroll
      for (int off = 1; off < 16; off <<= 1) m = fmaxf(m, __shfl_xor(m, off, 64));
      float z = 0.f;
      #pragma unroll
      for (int nt = 0; nt < 8; nt++) {
        float e = exp2f((s[nt][r] - m) * LOG2E);
        s[nt][r] = e; z += e;
      }
      #pragma unroll
      for (int off = 1; off < 16; off <<= 1) z += __shfl_xor(z, off, 64);
      mrow[r] = m; zrow[r] = z;
    }
    if (lm == 0) {
      #pragma unroll
      for (int r = 0; r < 4; r++) { hmax[nq][lr0 + r] = mrow[r]; hsum[nq][lr0 + r] = zrow[r]; }
    }
    __syncthreads();
    #pragma unroll
    for (int r = 0; r < 4; r++) {
      const int lr = lr0 + r;
      float M = fmaxf(fmaxf(hmax[0][lr], hmax[1][lr]), fmaxf(hmax[2][lr], hmax[3][lr]));
      float Z = hsum[0][lr] * exp2f((hmax[0][lr] - M) * LOG2E)
              + hsum[1][lr] * exp2f((hmax[1][lr] - M) * LOG2E)
              + hsum[2][lr] * exp2f((hmax[2][lr] - M) * LOG2E)
              + hsum[3][lr] * exp2f((hmax[3][lr] - M) * LOG2E);
      const float fac = exp2f((mrow[r] - M) * LOG2E) / Z;
      #pragma unroll
      for (int nt = 0; nt < 8; nt++) {
        const float w1 = s[nt][r] * fac;
        const float p = exp2f(w1 * LOG2E);
        lacc[r] += p;
        P[lr * 520 + nq * 128 + nt * 16 + lm] = f2bf(p);
      }
    }
    __syncthreads();
    const u16* Vb = vT + (nq * 128 + lm) * NTOK + c * CHK;
    const u16* Pb = &P[(mt * 16 + lm) * 520];
    for (int kk = 0; kk < CHK; kk += 32) {
      bf16x8 pf = *(const bf16x8*)(Pb + kk + quad * 8);
      #pragma unroll
      for (int nt = 0; nt < 8; nt++) {
        bf16x8 vf = *(const bf16x8*)(Vb + nt * 16 * NTOK + kk + quad * 8);
        oacc[nt] = __builtin_amdgcn_mfma_f32_16x16x32_bf16(pf, vf, oacc[nt], 0, 0, 0);
      }
    }
    __syncthreads();
  }
  #pragma unroll
  for (int r = 0; r < 4; r++) {
    float z = lacc[r];
    #pragma unroll
    for (int off = 1; off < 16; off <<= 1) z += __shfl_xor(z, off, 64);
    if (lm == 0) lpart[nq][lr0 + r] = z;
  }
  __syncthreads();
  #pragma unroll
  for (int r = 0; r < 4; r++) {
    const int lr = lr0 + r;
    const float linv = 1.0f / (lpart[0][lr] + lpart[1][lr] + lpart[2][lr] + lpart[3][lr]);
    #pragma unroll
    for (int nt = 0; nt < 8; nt++)
      attnb[(m0 + lr) * DD + nq * 128 + nt * 16 + lm] = f2bf(oacc[nt][r] * linv);
  }
}

// ---------------- cls row (exact fp32) ----------------
__global__ void cls_prep_kernel(const float* __restrict__ x, const float* __restrict__ Wq,
                                const float* __restrict__ bq, const float* __restrict__ Wk,
                                const float* __restrict__ bk, float* __restrict__ uc) {
  __shared__ float q0[512];
  int t = threadIdx.x;  // 512
  float acc = bq[t];
  for (int i = 0; i < 512; i++) acc += x[i] * Wq[i * 512 + t];
  q0[t] = acc;
  __syncthreads();
  float u = 0.f;
  for (int j = 0; j < 512; j++) u += Wk[t * 512 + j] * q0[j];
  uc[t] = u;
  if (t == 0) {
    float cc = 0.f;
    for (int j = 0; j < 512; j++) cc += bk[j] * q0[j];
    uc[512] = cc;
  }
}

__global__ void cls_scores_kernel(const float* __restrict__ x, const float* __restrict__ uc,
                                  float* __restrict__ s0) {
  __shared__ float u[512];
  __shared__ float c0s;
  int tid = threadIdx.x;  // 256
  for (int i = tid; i < 512; i += 256) u[i] = uc[i];
  if (tid == 0) c0s = uc[512];
  __syncthreads();
  int rowg = blockIdx.x * 32 + (tid >> 3);
  int ii = tid & 7;
  const float* xr = x + rowg * 512;
  float acc = 0.f;
  for (int i = ii; i < 512; i += 8) acc += xr[i] * u[i];
  acc += __shfl_xor(acc, 1, 64);
  acc += __shfl_xor(acc, 2, 64);
  acc += __shfl_xor(acc, 4, 64);
  if (ii == 0) s0[rowg] = (acc + c0s) * SCL;
}

__global__ void cls_softmax_kernel(const float* __restrict__ s0, float* __restrict__ out) {
  int tid = threadIdx.x;  // 1024 = 16 waves, wave w = chunk w
  int w = tid >> 6, lane = tid & 63;
  const float* sc = s0 + w * 512;
  float v[8];
  float m = -1e30f;
  #pragma unroll
  for (int j = 0; j < 8; j++) { v[j] = sc[lane * 8 + j]; m = fmaxf(m, v[j]); }
  for (int off = 1; off < 64; off <<= 1) m = fmaxf(m, __shfl_xor(m, off, 64));
  float z = 0.f;
  #pragma unroll
  for (int j = 0; j < 8; j++) { v[j] = expf(v[j] - m); z += v[j]; }
  for (int off = 1; off < 64; off <<= 1) z += __shfl_xor(z, off, 64);
  float invz = 1.f / z;
  float l = 0.f;
  #pragma unroll
  for (int j = 0; j < 8; j++) { v[j] = expf(v[j] * invz); l += v[j]; }
  for (int off = 1; off < 64; off <<= 1) l += __shfl_xor(l, off, 64);
  __shared__ float lw[16];
  if (lane == 0) lw[w] = l;
  __syncthreads();
  float L = 0.f;
  for (int i = 0; i < 16; i++) L += lw[i];
  float invL = 1.f / L;
  #pragma unroll
  for (int j = 0; j < 8; j++) out[w * 512 + lane * 8 + j] = v[j] * invL;
}

extern "C" void kernel_launch(void* const* d_in, const int* in_sizes, int n_in,
                              void* d_out, int out_size, void* d_ws, size_t ws_size,
                              hipStream_t stream) {
  const float* x  = (const float*)d_in[0];
  const float* Wq = (const float*)d_in[1];
  const float* bq = (const float*)d_in[2];
  const float* Wk = (const float*)d_in[3];
  const float* bk = (const float*)d_in[4];
  const float* Wv = (const float*)d_in[5];
  const float* bv = (const float*)d_in[6];
  const float* Wo = (const float*)d_in[7];
  const float* bo = (const float*)d_in[8];
  float* out = (float*)d_out;

  char* ws = (char*)d_ws;
  u16* xb    = (u16*)(ws);
  u16* WqT   = (u16*)(ws + 8388608);
  u16* WkT   = (u16*)(ws + 8912896);
  u16* WvT   = (u16*)(ws + 9437184);
  u16* WoT   = (u16*)(ws + 9961472);
  u16* qb    = (u16*)(ws + 10485760);
  u16* kb    = (u16*)(ws + 18874368);
  u16* vT    = (u16*)(ws + 27262976);
  u16* attnb = (u16*)(ws + 35651584);
  float* uc  = (float*)(ws + 44040192);   // 513 floats
  float* s0  = (float*)(ws + 44043264);   // 8192 floats
  float* lsum= (float*)(ws + 44076032);   // 8192 floats
  u16* P     = (u16*)(ws + 44108800);     // 8192*8192 bf16 = 128 MB
  const size_t ws_needed = 44108800ULL + (size_t)NTOK * NTOK * 2ULL;

  cast_x_kernel<<<4096, 256, 0, stream>>>(x, xb, NTOK * DD / 4);
  dim3 tb(32, 8), tg(16, 16);
  transW_kernel<<<tg, tb, 0, stream>>>(Wq, WqT);
  transW_kernel<<<tg, tb, 0, stream>>>(Wk, WkT);
  transW_kernel<<<tg, tb, 0, stream>>>(Wv, WvT);
  transW_kernel<<<tg, tb, 0, stream>>>(Wo, WoT);

  dim3 gg(NTOK / 128, DD / 128);
  gemm_lds_kernel<0><<<gg, 256, 0, stream>>>(xb, WqT, DD, DD, DD, bq, qb, nullptr, nullptr);
  gemm_lds_kernel<0><<<gg, 256, 0, stream>>>(xb, WkT, DD, DD, DD, bk, kb, nullptr, nullptr);
  gemm_lds_kernel<1><<<gg, 256, 0, stream>>>(xb, WvT, DD, DD, DD, bv, vT, nullptr, nullptr);

  if (ws_size >= ws_needed) {
    zero_l_kernel<<<32, 256, 0, stream>>>(lsum);
    dim3 sg(NTOK / 64, NCH);
    scores_kernel<<<sg, 512, 0, stream>>>(qb, kb, P, lsum);
    gemm_lds_kernel<3><<<gg, 256, 0, stream>>>(P, vT, NTOK, NTOK, NTOK, nullptr, attnb, nullptr, lsum);
  } else {
    attn_kernel<<<NTOK / 32, 512, 0, stream>>>(qb, kb, vT, attnb);
  }

  gemm_lds_kernel<2><<<gg, 256, 0, stream>>>(attnb, WoT, DD, DD, DD, bo, out, x, nullptr);

  cls_prep_kernel<<<1, 512, 0, stream>>>(x, Wq, bq, Wk, bk, uc);
  cls_scores_kernel<<<NTOK / 32, 256, 0, stream>>>(x, uc, s0);
  cls_softmax_kernel<<<1, 1024, 0, stream>>>(s0, out + (size_t)NTOK * DD);
}

// Round 3
// 414.433 us; speedup vs baseline: 3.0105x; 1.2850x over previous
//
#include <hip/hip_runtime.h>
#include <stdint.h>

typedef unsigned short u16;
typedef __bf16 bf16x8 __attribute__((ext_vector_type(8)));
typedef float f32x4 __attribute__((ext_vector_type(4)));

#define NTOK 8192
#define DD 512
#define CHK 512
#define NCH 16
#define KSPLIT 4
#define KLEN 2048
#define LOG2E 1.4426950408889634f
#define SCL 0.044194173824159216f          // 1/sqrt(512)
#define SCLL 0.063762069130835270f         // SCL * LOG2E

__device__ __forceinline__ u16 f2bf(float f) {
  union { float f; uint32_t u; } v; v.f = f;
  uint32_t r = v.u + 0x7FFFu + ((v.u >> 16) & 1u);
  return (u16)(r >> 16);
}

// async global->LDS, 16B per lane. LDS dest is wave-uniform base + lane*16.
typedef const __attribute__((address_space(1))) unsigned int* gas_t;
typedef __attribute__((address_space(3))) unsigned int* las_t;
__device__ __forceinline__ void gload16(const void* g, void* l) {
  __builtin_amdgcn_global_load_lds((gas_t)g, (las_t)l, 16, 0, 0);
}

// ---------------- cast x -> bf16 ----------------
__global__ void cast_x_kernel(const float* __restrict__ x, u16* __restrict__ xb, int n4) {
  int i = blockIdx.x * blockDim.x + threadIdx.x;
  if (i >= n4) return;
  float4 v = ((const float4*)x)[i];
  ushort4 o;
  o.x = f2bf(v.x); o.y = f2bf(v.y); o.z = f2bf(v.z); o.w = f2bf(v.w);
  ((ushort4*)xb)[i] = o;
}

// ---------------- transpose all 4 weights (fp32) -> bf16 [n][k], one launch ----------------
__global__ void transW4_kernel(const float* __restrict__ Wq, const float* __restrict__ Wk,
                               const float* __restrict__ Wv, const float* __restrict__ Wo,
                               u16* __restrict__ Wall, u16* __restrict__ WoT) {
  const float* W; u16* WT;
  if (blockIdx.z == 0)      { W = Wq; WT = Wall; }
  else if (blockIdx.z == 1) { W = Wk; WT = Wall + 512 * 512; }
  else if (blockIdx.z == 2) { W = Wv; WT = Wall + 2 * 512 * 512; }
  else                      { W = Wo; WT = WoT; }
  __shared__ float t[32][33];
  int k0 = blockIdx.y * 32, n0 = blockIdx.x * 32;
  int tx = threadIdx.x, ty = threadIdx.y;  // 32 x 8
  #pragma unroll
  for (int i = 0; i < 4; i++)
    t[ty + 8 * i][tx] = W[(k0 + ty + 8 * i) * DD + n0 + tx];
  __syncthreads();
  #pragma unroll
  for (int i = 0; i < 4; i++)
    WT[(n0 + ty + 8 * i) * DD + k0 + tx] = f2bf(t[tx][ty + 8 * i]);
}

__global__ void zero_l_kernel(float* __restrict__ l) {
  l[blockIdx.x * 256 + threadIdx.x] = 0.f;
}

// ---------------- fused q/k/v projection: A[8192x512] @ WallT[1536x512]^T ----------------
// by: 0..11; which = by>>2 (0=q scaled by SCLL, 1=k, 2=v transposed out)
__launch_bounds__(256, 3)
__global__ void qkv_kernel(const u16* __restrict__ A, const u16* __restrict__ Wall,
                           const float* __restrict__ bq, const float* __restrict__ bk,
                           const float* __restrict__ bv, u16* __restrict__ qb,
                           u16* __restrict__ kb, u16* __restrict__ vT) {
  __shared__ __align__(16) u16 As[128 * 32];
  __shared__ __align__(16) u16 Bs[128 * 32];
  const int m0 = blockIdx.x * 128;
  const int n0g = blockIdx.y * 128;          // 0..1535
  const int which = blockIdx.y >> 2;
  const int n0 = n0g & 511;
  const int tid = threadIdx.x;
  const int w = tid >> 6, lane = tid & 63, lm = lane & 15, quad = lane >> 4;
  const int wm = w & 1, wn = w >> 1;
  f32x4 acc[4][4] = {};
  const int soff = tid * 16;
  const int srow = soff >> 6;
  const int scol = soff & 63;
  const char* Ag = (const char*)A + ((size_t)(m0 + srow) * DD) * 2 + scol;
  const char* Bg = (const char*)Wall + ((size_t)(n0g + srow) * DD) * 2 + scol;
  char* Al = (char*)As + w * 1024;
  char* Bl = (char*)Bs + w * 1024;
  const size_t rs = (size_t)64 * DD * 2;
  for (int kk = 0; kk < DD; kk += 32) {
    const char* ag = Ag + (size_t)kk * 2;
    const char* bg = Bg + (size_t)kk * 2;
    gload16(ag, Al);
    gload16(ag + rs, Al + 4096);
    gload16(bg, Bl);
    gload16(bg + rs, Bl + 4096);
    __syncthreads();
    bf16x8 af[4], bfr[4];
    #pragma unroll
    for (int i = 0; i < 4; i++) af[i] = *(const bf16x8*)&As[(wm * 64 + i * 16 + lm) * 32 + quad * 8];
    #pragma unroll
    for (int j = 0; j < 4; j++) bfr[j] = *(const bf16x8*)&Bs[(wn * 64 + j * 16 + lm) * 32 + quad * 8];
    #pragma unroll
    for (int i = 0; i < 4; i++)
      #pragma unroll
      for (int j = 0; j < 4; j++)
        acc[i][j] = __builtin_amdgcn_mfma_f32_16x16x32_bf16(af[i], bfr[j], acc[i][j], 0, 0, 0);
    __syncthreads();
  }
  const float* bias = (which == 0) ? bq : (which == 1) ? bk : bv;
  #pragma unroll
  for (int i = 0; i < 4; i++) {
    const int row0 = m0 + wm * 64 + i * 16 + quad * 4;
    #pragma unroll
    for (int j = 0; j < 4; j++) {
      const int col = n0 + wn * 64 + j * 16 + lm;
      const float bv_ = bias[col];
      if (which == 0) {
        #pragma unroll
        for (int r = 0; r < 4; r++)
          qb[(size_t)(row0 + r) * DD + col] = f2bf((acc[i][j][r] + bv_) * SCLL);
      } else if (which == 1) {
        #pragma unroll
        for (int r = 0; r < 4; r++)
          kb[(size_t)(row0 + r) * DD + col] = f2bf(acc[i][j][r] + bv_);
      } else {
        ushort4 o;
        o.x = f2bf(acc[i][j][0] + bv_); o.y = f2bf(acc[i][j][1] + bv_);
        o.z = f2bf(acc[i][j][2] + bv_); o.w = f2bf(acc[i][j][3] + bv_);
        *(ushort4*)(vT + (size_t)col * NTOK + row0) = o;
      }
    }
  }
}

// ---------------- general LDS GEMM ----------------
// MODE 2: fp32 out + bias + resid (out projection)
// MODE 3: bf16 out row-major, scaled by 1/lsum[row] (PV, no split-K fallback)
// MODE 4: fp32 partial out, K-range by blockIdx.z (split-K PV)
template <int MODE>
__launch_bounds__(256, 3)
__global__ void gemm_lds_kernel(const u16* __restrict__ A, const u16* __restrict__ BT,
                                int K, int lda, int ldb,
                                const float* __restrict__ bias, void* __restrict__ outp,
                                const float* __restrict__ resid, const float* __restrict__ lsum) {
  __shared__ __align__(16) u16 As[128 * 32];
  __shared__ __align__(16) u16 Bs[128 * 32];
  const int m0 = blockIdx.x * 128, n0 = blockIdx.y * 128;
  const int tid = threadIdx.x;
  const int w = tid >> 6, lane = tid & 63, lm = lane & 15, quad = lane >> 4;
  const int wm = w & 1, wn = w >> 1;
  f32x4 acc[4][4] = {};
  const int soff = tid * 16;
  const int srow = soff >> 6;
  const int scol = soff & 63;
  const size_t kbase = (MODE == 4) ? (size_t)blockIdx.z * (size_t)K : 0;
  const char* Ag = (const char*)A + ((size_t)(m0 + srow) * lda + kbase) * 2 + scol;
  const char* Bg = (const char*)BT + ((size_t)(n0 + srow) * ldb + kbase) * 2 + scol;
  char* Al = (char*)As + w * 1024;
  char* Bl = (char*)Bs + w * 1024;
  const size_t ars = (size_t)64 * lda * 2;
  const size_t brs = (size_t)64 * ldb * 2;
  for (int kk = 0; kk < K; kk += 32) {
    const char* ag = Ag + (size_t)kk * 2;
    const char* bg = Bg + (size_t)kk * 2;
    gload16(ag, Al);
    gload16(ag + ars, Al + 4096);
    gload16(bg, Bl);
    gload16(bg + brs, Bl + 4096);
    __syncthreads();
    bf16x8 af[4], bfr[4];
    #pragma unroll
    for (int i = 0; i < 4; i++) af[i] = *(const bf16x8*)&As[(wm * 64 + i * 16 + lm) * 32 + quad * 8];
    #pragma unroll
    for (int j = 0; j < 4; j++) bfr[j] = *(const bf16x8*)&Bs[(wn * 64 + j * 16 + lm) * 32 + quad * 8];
    #pragma unroll
    for (int i = 0; i < 4; i++)
      #pragma unroll
      for (int j = 0; j < 4; j++)
        acc[i][j] = __builtin_amdgcn_mfma_f32_16x16x32_bf16(af[i], bfr[j], acc[i][j], 0, 0, 0);
    __syncthreads();
  }
  #pragma unroll
  for (int i = 0; i < 4; i++) {
    const int row0 = m0 + wm * 64 + i * 16 + quad * 4;
    float li[4];
    if (MODE == 3) {
      #pragma unroll
      for (int r = 0; r < 4; r++) li[r] = 1.0f / lsum[row0 + r];
    }
    #pragma unroll
    for (int j = 0; j < 4; j++) {
      const int col = n0 + wn * 64 + j * 16 + lm;
      if (MODE == 2) {
        const float bv = bias[col];
        #pragma unroll
        for (int r = 0; r < 4; r++) {
          const size_t idx = (size_t)(row0 + r) * DD + col;
          ((float*)outp)[idx] = acc[i][j][r] + bv + resid[idx];
        }
      } else if (MODE == 3) {
        #pragma unroll
        for (int r = 0; r < 4; r++)
          ((u16*)outp)[(size_t)(row0 + r) * DD + col] = f2bf(acc[i][j][r] * li[r]);
      } else {  // MODE 4
        float* po = (float*)outp + (size_t)blockIdx.z * NTOK * DD;
        #pragma unroll
        for (int r = 0; r < 4; r++)
          po[(size_t)(row0 + r) * DD + col] = acc[i][j][r];
      }
    }
  }
}

// ---------------- split-K PV reduce: attnb = (sum parts) / lsum ----------------
__global__ void pv_reduce_kernel(const float* __restrict__ part, const float* __restrict__ lsum,
                                 u16* __restrict__ attnb) {
  const int idx = blockIdx.x * 256 + threadIdx.x;  // over 4M/4 groups
  const int row = idx >> 7;
  const int c4 = (idx & 127) << 2;
  const float* p = part + (size_t)row * DD + c4;
  const size_t stride = (size_t)NTOK * DD;
  float4 a = *(const float4*)(p);
  float4 b = *(const float4*)(p + stride);
  float4 c = *(const float4*)(p + 2 * stride);
  float4 d = *(const float4*)(p + 3 * stride);
  const float inv = 1.0f / lsum[row];
  ushort4 o;
  o.x = f2bf((a.x + b.x + c.x + d.x) * inv);
  o.y = f2bf((a.y + b.y + c.y + d.y) * inv);
  o.z = f2bf((a.z + b.z + c.z + d.z) * inv);
  o.w = f2bf((a.w + b.w + c.w + d.w) * inv);
  *(ushort4*)(attnb + (size_t)row * DD + c4) = o;
}

// ---------------- pass A: S' = Qs@K^T (q pre-scaled by SCL*LOG2E), max-free chunk softmax ----------------
// 512 threads = 8 waves; block tile 64 rows x 512 cols (one full chunk); wave w owns cols [w*64, w*64+64)
__launch_bounds__(512, 4)
__global__ void scores_kernel(const u16* __restrict__ qb, const u16* __restrict__ kb,
                              u16* __restrict__ P, float* __restrict__ lsum) {
  __shared__ __align__(16) u16 As[64 * 32];    // 4 KB
  __shared__ __align__(16) u16 Bs[512 * 32];   // 32 KB
  __shared__ float hS[8][64], hP[8][64], hZ[64];
  const int m0 = blockIdx.x * 64;
  const int c = blockIdx.y;
  const int tid = threadIdx.x;
  const int w = tid >> 6, lane = tid & 63, lm = lane & 15, quad = lane >> 4;
  f32x4 s[4][4] = {};
  const int soff = tid * 16;
  const int srow = soff >> 6;
  const int scol = soff & 63;
  const char* Qg = (const char*)qb + ((size_t)(m0 + srow) * DD) * 2 + scol;
  const char* Kg = (const char*)kb + ((size_t)(c * CHK + srow) * DD) * 2 + scol;
  const size_t krs = (size_t)128 * DD * 2;
  char* Al = (char*)As + w * 1024;
  char* Bl = (char*)Bs + w * 1024;
  for (int kk = 0; kk < DD; kk += 32) {
    if (tid < 256) gload16(Qg + (size_t)kk * 2, Al);
    #pragma unroll
    for (int r = 0; r < 4; r++)
      gload16(Kg + (size_t)kk * 2 + r * krs, Bl + r * 8192);
    __syncthreads();
    bf16x8 af[4], bfr[4];
    #pragma unroll
    for (int i = 0; i < 4; i++) af[i] = *(const bf16x8*)&As[(i * 16 + lm) * 32 + quad * 8];
    #pragma unroll
    for (int j = 0; j < 4; j++) bfr[j] = *(const bf16x8*)&Bs[(w * 64 + j * 16 + lm) * 32 + quad * 8];
    #pragma unroll
    for (int i = 0; i < 4; i++)
      #pragma unroll
      for (int j = 0; j < 4; j++)
        s[i][j] = __builtin_amdgcn_mfma_f32_16x16x32_bf16(af[i], bfr[j], s[i][j], 0, 0, 0);
    __syncthreads();
  }
  // ---- phase A: e = exp(s) (acc already holds s*log2e); per-wave partial row sums ----
  #pragma unroll
  for (int i = 0; i < 4; i++) {
    #pragma unroll
    for (int reg = 0; reg < 4; reg++) {
      float z = 0.f;
      #pragma unroll
      for (int j = 0; j < 4; j++) {
        float e = exp2f(s[i][j][reg]);
        s[i][j][reg] = e;
        z += e;
      }
      #pragma unroll
      for (int off = 1; off < 16; off <<= 1) z += __shfl_xor(z, off, 64);
      if (lm == 0) hS[w][i * 16 + quad * 4 + reg] = z;
    }
  }
  __syncthreads();
  // ---- phase B: row totals -> hZ = LOG2E / Z ----
  if (tid < 64) {
    float t = 0.f;
    #pragma unroll
    for (int w2 = 0; w2 < 8; w2++) t += hS[w2][tid];
    hZ[tid] = LOG2E / t;
  }
  __syncthreads();
  // ---- phase C: p = exp(e/Z) = exp2(e * hZ); store P; partial second-softmax sums ----
  #pragma unroll
  for (int i = 0; i < 4; i++) {
    #pragma unroll
    for (int reg = 0; reg < 4; reg++) {
      const int rl = i * 16 + quad * 4 + reg;
      const float iz = hZ[rl];
      float zp = 0.f;
      u16* Pr = P + (size_t)(m0 + rl) * NTOK + c * CHK + w * 64;
      #pragma unroll
      for (int j = 0; j < 4; j++) {
        const float p = exp2f(s[i][j][reg] * iz);
        zp += p;
        Pr[j * 16 + lm] = f2bf(p);
      }
      #pragma unroll
      for (int off = 1; off < 16; off <<= 1) zp += __shfl_xor(zp, off, 64);
      if (lm == 0) hP[w][rl] = zp;
    }
  }
  __syncthreads();
  if (tid < 64) {
    float t = 0.f;
    #pragma unroll
    for (int w2 = 0; w2 < 8; w2++) t += hP[w2][tid];
    atomicAdd(&lsum[m0 + tid], t);
  }
}

// ---------------- last-resort fused attention (qb pre-scaled by SCL*LOG2E) ----------------
__launch_bounds__(512, 2)
__global__ void attn_kernel(const u16* __restrict__ qb, const u16* __restrict__ kb,
                            const u16* __restrict__ vT, u16* __restrict__ attnb) {
  __shared__ __align__(16) u16 P[32 * 520];
  __shared__ float hmax[4][32];
  __shared__ float hsum[4][32];
  __shared__ float lpart[4][32];
  const int m0 = blockIdx.x * 32;
  const int tid = threadIdx.x;
  const int w = tid >> 6, lane = tid & 63;
  const int lm = lane & 15, quad = lane >> 4;
  const int mt = w & 1, nq = w >> 1;
  const u16* Ab = qb + (m0 + mt * 16 + lm) * DD;
  const int lr0 = mt * 16 + quad * 4;
  f32x4 oacc[8] = {};
  float lacc[4] = {0.f, 0.f, 0.f, 0.f};
  for (int c = 0; c < NCH; c++) {
    f32x4 s[8] = {};
    const u16* Kb = kb + (c * CHK + nq * 128 + lm) * DD;
    for (int kk = 0; kk < DD; kk += 32) {
      bf16x8 af = *(const bf16x8*)(Ab + kk + quad * 8);
      #pragma unroll
      for (int nt = 0; nt < 8; nt++) {
        bf16x8 bfr = *(const bf16x8*)(Kb + nt * 16 * DD + kk + quad * 8);
        s[nt] = __builtin_amdgcn_mfma_f32_16x16x32_bf16(af, bfr, s[nt], 0, 0, 0);
      }
    }
    float mrow[4], zrow[4];
    #pragma unroll
    for (int r = 0; r < 4; r++) {
      float m = -1e30f;
      #pragma unroll
      for (int nt = 0; nt < 8; nt++) m = fmaxf(m, s[nt][r]);
      #pragma unroll
      for (int off = 1; off < 16; off <<= 1) m = fmaxf(m, __shfl_xor(m, off, 64));
      float z = 0.f;
      #pragma unroll
      for (int nt = 0; nt < 8; nt++) {
        float e = exp2f(s[nt][r] - m);
        s[nt][r] = e; z += e;
      }
      #pragma unroll
      for (int off = 1; off < 16; off <<= 1) z += __shfl_xor(z, off, 64);
      mrow[r] = m; zrow[r] = z;
    }
    if (lm == 0) {
      #pragma unroll
      for (int r = 0; r < 4; r++) { hmax[nq][lr0 + r] = mrow[r]; hsum[nq][lr0 + r] = zrow[r]; }
    }
    __syncthreads();
    #pragma unroll
    for (int r = 0; r < 4; r++) {
      const int lr = lr0 + r;
      float M = fmaxf(fmaxf(hmax[0][lr], hmax[1][lr]), fmaxf(hmax[2][lr], hmax[3][lr]));
      float Z = hsum[0][lr] * exp2f(hmax[0][lr] - M)
              + hsum[1][lr] * exp2f(hmax[1][lr] - M)
              + hsum[2][lr] * exp2f(hmax[2][lr] - M)
              + hsum[3][lr] * exp2f(hmax[3][lr] - M);
      const float fac = exp2f(mrow[r] - M) / Z;
      #pragma unroll
      for (int nt = 0; nt < 8; nt++) {
        const float w1 = s[nt][r] * fac;
        const float p = exp2f(w1 * LOG2E);
        lacc[r] += p;
        P[lr * 520 + nq * 128 + nt * 16 + lm] = f2bf(p);
      }
    }
    __syncthreads();
    const u16* Vb = vT + (nq * 128 + lm) * NTOK + c * CHK;
    const u16* Pb = &P[(mt * 16 + lm) * 520];
    for (int kk = 0; kk < CHK; kk += 32) {
      bf16x8 pf = *(const bf16x8*)(Pb + kk + quad * 8);
      #pragma unroll
      for (int nt = 0; nt < 8; nt++) {
        bf16x8 vf = *(const bf16x8*)(Vb + nt * 16 * NTOK + kk + quad * 8);
        oacc[nt] = __builtin_amdgcn_mfma_f32_16x16x32_bf16(pf, vf, oacc[nt], 0, 0, 0);
      }
    }
    __syncthreads();
  }
  #pragma unroll
  for (int r = 0; r < 4; r++) {
    float z = lacc[r];
    #pragma unroll
    for (int off = 1; off < 16; off <<= 1) z += __shfl_xor(z, off, 64);
    if (lm == 0) lpart[nq][lr0 + r] = z;
  }
  __syncthreads();
  #pragma unroll
  for (int r = 0; r < 4; r++) {
    const int lr = lr0 + r;
    const float linv = 1.0f / (lpart[0][lr] + lpart[1][lr] + lpart[2][lr] + lpart[3][lr]);
    #pragma unroll
    for (int nt = 0; nt < 8; nt++)
      attnb[(m0 + lr) * DD + nq * 128 + nt * 16 + lm] = f2bf(oacc[nt][r] * linv);
  }
}

// ---------------- cls row (exact fp32) ----------------
__global__ void cls_prep_kernel(const float* __restrict__ x, const float* __restrict__ Wq,
                                const float* __restrict__ bq, const float* __restrict__ Wk,
                                const float* __restrict__ bk, float* __restrict__ uc) {
  __shared__ float q0[512];
  int t = threadIdx.x;  // 512
  float acc = bq[t];
  for (int i = 0; i < 512; i++) acc += x[i] * Wq[i * 512 + t];
  q0[t] = acc;
  __syncthreads();
  float u = 0.f;
  for (int j = 0; j < 512; j++) u += Wk[t * 512 + j] * q0[j];
  uc[t] = u;
  if (t == 0) {
    float cc = 0.f;
    for (int j = 0; j < 512; j++) cc += bk[j] * q0[j];
    uc[512] = cc;
  }
}

__global__ void cls_scores_kernel(const float* __restrict__ x, const float* __restrict__ uc,
                                  float* __restrict__ s0) {
  __shared__ float u[512];
  __shared__ float c0s;
  int tid = threadIdx.x;  // 256
  for (int i = tid; i < 512; i += 256) u[i] = uc[i];
  if (tid == 0) c0s = uc[512];
  __syncthreads();
  int rowg = blockIdx.x * 32 + (tid >> 3);
  int ii = tid & 7;
  const float* xr = x + rowg * 512;
  float acc = 0.f;
  for (int i = ii; i < 512; i += 8) acc += xr[i] * u[i];
  acc += __shfl_xor(acc, 1, 64);
  acc += __shfl_xor(acc, 2, 64);
  acc += __shfl_xor(acc, 4, 64);
  if (ii == 0) s0[rowg] = (acc + c0s) * SCL;
}

__global__ void cls_softmax_kernel(const float* __restrict__ s0, float* __restrict__ out) {
  int tid = threadIdx.x;  // 1024 = 16 waves, wave w = chunk w
  int w = tid >> 6, lane = tid & 63;
  const float* sc = s0 + w * 512;
  float v[8];
  float m = -1e30f;
  #pragma unroll
  for (int j = 0; j < 8; j++) { v[j] = sc[lane * 8 + j]; m = fmaxf(m, v[j]); }
  for (int off = 1; off < 64; off <<= 1) m = fmaxf(m, __shfl_xor(m, off, 64));
  float z = 0.f;
  #pragma unroll
  for (int j = 0; j < 8; j++) { v[j] = expf(v[j] - m); z += v[j]; }
  for (int off = 1; off < 64; off <<= 1) z += __shfl_xor(z, off, 64);
  float invz = 1.f / z;
  float l = 0.f;
  #pragma unroll
  for (int j = 0; j < 8; j++) { v[j] = expf(v[j] * invz); l += v[j]; }
  for (int off = 1; off < 64; off <<= 1) l += __shfl_xor(l, off, 64);
  __shared__ float lw[16];
  if (lane == 0) lw[w] = l;
  __syncthreads();
  float L = 0.f;
  for (int i = 0; i < 16; i++) L += lw[i];
  float invL = 1.f / L;
  #pragma unroll
  for (int j = 0; j < 8; j++) out[w * 512 + lane * 8 + j] = v[j] * invL;
}

extern "C" void kernel_launch(void* const* d_in, const int* in_sizes, int n_in,
                              void* d_out, int out_size, void* d_ws, size_t ws_size,
                              hipStream_t stream) {
  const float* x  = (const float*)d_in[0];
  const float* Wq = (const float*)d_in[1];
  const float* bq = (const float*)d_in[2];
  const float* Wk = (const float*)d_in[3];
  const float* bk = (const float*)d_in[4];
  const float* Wv = (const float*)d_in[5];
  const float* bv = (const float*)d_in[6];
  const float* Wo = (const float*)d_in[7];
  const float* bo = (const float*)d_in[8];
  float* out = (float*)d_out;

  char* ws = (char*)d_ws;
  u16* xb    = (u16*)(ws);                  // 8 MB
  u16* Wall  = (u16*)(ws + 8388608);        // 3x512x512 bf16 = 1.5 MB
  u16* WoT   = (u16*)(ws + 9961472);        // 512 KB
  u16* qb    = (u16*)(ws + 10485760);       // 8 MB (pre-scaled by SCL*LOG2E)
  u16* kb    = (u16*)(ws + 18874368);       // 8 MB
  u16* vT    = (u16*)(ws + 27262976);       // 8 MB
  u16* attnb = (u16*)(ws + 35651584);       // 8 MB
  float* uc  = (float*)(ws + 44040192);     // 513 floats
  float* s0  = (float*)(ws + 44043264);     // 8192 floats
  float* lsum= (float*)(ws + 44076032);     // 8192 floats
  u16* P     = (u16*)(ws + 44108800);       // 128 MB
  float* part= (float*)(ws + 178326528);    // 4 x 16 MB = 64 MB
  const size_t need_P    = 178326528ULL;
  const size_t need_full = 178326528ULL + (size_t)KSPLIT * NTOK * DD * 4ULL;

  cast_x_kernel<<<4096, 256, 0, stream>>>(x, xb, NTOK * DD / 4);
  transW4_kernel<<<dim3(16, 16, 4), dim3(32, 8), 0, stream>>>(Wq, Wk, Wv, Wo, Wall, WoT);

  qkv_kernel<<<dim3(NTOK / 128, 12), 256, 0, stream>>>(xb, Wall, bq, bk, bv, qb, kb, vT);

  if (ws_size >= need_P) {
    zero_l_kernel<<<32, 256, 0, stream>>>(lsum);
    scores_kernel<<<dim3(NTOK / 64, NCH), 512, 0, stream>>>(qb, kb, P, lsum);
    if (ws_size >= need_full) {
      gemm_lds_kernel<4><<<dim3(NTOK / 128, DD / 128, KSPLIT), 256, 0, stream>>>(
          P, vT, KLEN, NTOK, NTOK, nullptr, part, nullptr, nullptr);
      pv_reduce_kernel<<<NTOK * DD / 4 / 256, 256, 0, stream>>>(part, lsum, attnb);
    } else {
      gemm_lds_kernel<3><<<dim3(NTOK / 128, DD / 128), 256, 0, stream>>>(
          P, vT, NTOK, NTOK, NTOK, nullptr, attnb, nullptr, lsum);
    }
  } else {
    attn_kernel<<<NTOK / 32, 512, 0, stream>>>(qb, kb, vT, attnb);
  }

  gemm_lds_kernel<2><<<dim3(NTOK / 128, DD / 128), 256, 0, stream>>>(
      attnb, WoT, DD, DD, DD, bo, out, x, nullptr);

  cls_prep_kernel<<<1, 512, 0, stream>>>(x, Wq, bq, Wk, bk, uc);
  cls_scores_kernel<<<NTOK / 32, 256, 0, stream>>>(x, uc, s0);
  cls_softmax_kernel<<<1, 1024, 0, stream>>>(s0, out + (size_t)NTOK * DD);
}